// Round 2
// baseline (547.002 us; speedup 1.0000x reference)
//
#include <hip/hip_runtime.h>
#include <stdint.h>

typedef unsigned short u16;
typedef u16 u16x4 __attribute__((ext_vector_type(4)));
typedef u16 u16x8 __attribute__((ext_vector_type(8)));
typedef __bf16 bf16x8 __attribute__((ext_vector_type(8)));
typedef float f32x4 __attribute__((ext_vector_type(4)));

#define S_LEN 1024
#define D_LEN 64
#define TQ 32

__device__ __forceinline__ u16 f2bf(float f) {
    union { float f; uint32_t u; } c; c.f = f;
    uint32_t r = (c.u + 0x7FFFu + ((c.u >> 16) & 1u)) >> 16;   // RNE
    return (u16)r;
}

// v (fp32) -> vs (bf16) swizzled: vs[bh][k>>3][d][k&7], so one MFMA B-fragment
// (8 bf16 along k) is a single contiguous 16B load. Reads coalesced over d.
__global__ __launch_bounds__(256) void vswz_kernel(const float* __restrict__ v,
                                                   u16* __restrict__ vs) {
    int tid = blockIdx.x * 256 + threadIdx.x;   // 96*128*64 = 786432
    int d  = tid & 63;
    int kb = (tid >> 6) & 127;
    int bh = tid >> 13;
    const float* src = v + (size_t)bh * (S_LEN * D_LEN) + (size_t)kb * 8 * D_LEN + d;
    u16x8 t;
#pragma unroll
    for (int j = 0; j < 8; ++j) t[j] = f2bf(src[(size_t)j * D_LEN]);
    *(u16x8*)(vs + (size_t)tid * 8) = t;
}

// One block: 32 q-rows of one (b,h). fp32 bias+softmax fused on registers from
// coalesced float4 loads; normalized P written to LDS as bf16 with a 16B-chunk
// XOR swizzle (phys16 = chunk16 ^ (row&7)) to break the A-fragment bank
// conflict. PV via bf16 MFMA, fp32 stores.
__global__ __launch_bounds__(256) void attn_kernel(const float* __restrict__ scores,
                                                   const float* __restrict__ bias,
                                                   const u16* __restrict__ vs,
                                                   float* __restrict__ out) {
    __shared__ u16 s_p[TQ * S_LEN];   // 64 KB bf16 P tile

    const int bh = blockIdx.x >> 5;
    const int q0 = (blockIdx.x & 31) * TQ;
    const int tid = threadIdx.x;
    const int wave = tid >> 6;
    const int lane = tid & 63;

    const float* sg = scores + (size_t)bh * (S_LEN * S_LEN) + (size_t)q0 * S_LEN;

    // bias: lane covers cols c*256 + lane*4 + j
    f32x4 bv[4];
#pragma unroll
    for (int c = 0; c < 4; ++c)
        bv[c] = *(const f32x4*)(bias + c * 256 + lane * 4);

    // ---- fused bias + softmax: wave w owns rows w*8 .. w*8+7 ----
#pragma unroll
    for (int rr = 0; rr < 8; ++rr) {
        int r = wave * 8 + rr;
        const float* rowp = sg + (size_t)r * S_LEN;
        f32x4 xv[4];
#pragma unroll
        for (int c = 0; c < 4; ++c) {
            f32x4 t = *(const f32x4*)(rowp + c * 256 + lane * 4);
            xv[c] = t + bv[c];
        }
        float m = xv[0][0];
#pragma unroll
        for (int c = 0; c < 4; ++c)
#pragma unroll
            for (int j = 0; j < 4; ++j) m = fmaxf(m, xv[c][j]);
#pragma unroll
        for (int off = 32; off > 0; off >>= 1) m = fmaxf(m, __shfl_xor(m, off, 64));
        float sum = 0.f;
        f32x4 ev[4];
#pragma unroll
        for (int c = 0; c < 4; ++c)
#pragma unroll
            for (int j = 0; j < 4; ++j) {
                float e = __expf(xv[c][j] - m);
                ev[c][j] = e; sum += e;
            }
#pragma unroll
        for (int off = 32; off > 0; off >>= 1) sum += __shfl_xor(sum, off, 64);
        float rinv = 1.0f / sum;
#pragma unroll
        for (int c = 0; c < 4; ++c) {
            u16x4 p;
#pragma unroll
            for (int j = 0; j < 4; ++j) p[j] = f2bf(ev[c][j] * rinv);
            int cb  = c * 64 + lane;                 // 8B-chunk index (col/4)
            int p16 = ((cb >> 1) ^ (r & 7));         // swizzled 16B-chunk
            int off8 = r * S_LEN + (p16 << 3) + ((cb & 1) << 2);
            *(u16x4*)(&s_p[off8]) = p;
        }
    }

    __syncthreads();

    // ---- PV: wave w owns d-cols [16w,16w+16), two 16-row M-tiles ----
    const int n0 = wave * 16;
    const int q  = lane >> 4;       // quad: k-octet selector
    const int tl = lane & 15;       // A: m / B: n / C: col
    f32x4 acc0 = {0.f, 0.f, 0.f, 0.f};
    f32x4 acc1 = {0.f, 0.f, 0.f, 0.f};
    const u16* vb = vs + (size_t)bh * (S_LEN * D_LEN) + (size_t)(n0 + tl) * 8;

#pragma unroll 4
    for (int kt = 0; kt < 32; ++kt) {
        int kb = kt * 4 + q;                       // k-octet index (k>>3)
        int cA = (kb ^ (tl & 7)) << 3;             // swizzled LDS element offset
        bf16x8 a0  = __builtin_bit_cast(bf16x8, *(const u16x8*)(&s_p[tl * S_LEN + cA]));
        bf16x8 a1v = __builtin_bit_cast(bf16x8, *(const u16x8*)(&s_p[(tl + 16) * S_LEN + cA]));
        bf16x8 bb  = __builtin_bit_cast(bf16x8, *(const u16x8*)(vb + (size_t)kb * (D_LEN * 8)));
        acc0 = __builtin_amdgcn_mfma_f32_16x16x32_bf16(a0,  bb, acc0, 0, 0, 0);
        acc1 = __builtin_amdgcn_mfma_f32_16x16x32_bf16(a1v, bb, acc1, 0, 0, 0);
    }

    // ---- epilogue: C/D layout col=lane&15, row=(lane>>4)*4+reg ----
    float* ob = out + ((size_t)(bh * S_LEN + q0)) * D_LEN + n0 + tl;
#pragma unroll
    for (int j = 0; j < 4; ++j) {
        int row0 = q * 4 + j;
        ob[(size_t)row0 * D_LEN]        = acc0[j];
        ob[(size_t)(row0 + 16) * D_LEN] = acc1[j];
    }
}

extern "C" void kernel_launch(void* const* d_in, const int* in_sizes, int n_in,
                              void* d_out, int out_size, void* d_ws, size_t ws_size,
                              hipStream_t stream) {
    const float* scores = (const float*)d_in[0];
    const float* v      = (const float*)d_in[1];
    const float* bias   = (const float*)d_in[2];
    float* outp = (float*)d_out;
    u16*   vs   = (u16*)d_ws;          // 12.58 MB swizzled bf16 copy of v

    vswz_kernel<<<3072, 256, 0, stream>>>(v, vs);
    attn_kernel<<<3072, 256, 0, stream>>>(scores, bias, vs, outp);
}